// Round 2
// baseline (1797.553 us; speedup 1.0000x reference)
//
#include <hip/hip_runtime.h>
#include <cmath>

#define MSG 128
#define TILE_M 64
#define LDSTRIDE 136  // bf16 elements per LDS row (128 + 8 pad, keeps 16B align)

typedef __attribute__((ext_vector_type(8))) __bf16 bf16x8;
typedef __attribute__((ext_vector_type(4))) float f32x4;

__device__ __forceinline__ unsigned short f2bf_rne(float f) {
  unsigned u = __float_as_uint(f);
  unsigned r = u + 0x7FFFu + ((u >> 16) & 1u);
  return (unsigned short)(r >> 16);
}

// Pack two floats -> two bf16 (truncate) in ONE v_perm_b32.
__device__ __forceinline__ unsigned pack2bf_trunc(float lo, float hi) {
  return __builtin_amdgcn_perm(__float_as_uint(hi), __float_as_uint(lo), 0x07060302u);
}

// ---- Kernel 1: transpose+convert weight matrices to bf16; pack x into float4.
__global__ void prep_kernel(const float* __restrict__ Ww1, const float* __restrict__ Wa1,
                            const float* __restrict__ x,
                            unsigned short* __restrict__ WtW, unsigned short* __restrict__ WtA,
                            float4* __restrict__ x4, int N) {
  int idx = blockIdx.x * blockDim.x + threadIdx.x;
  if (idx < MSG * MSG) {
    int k = idx >> 7, n = idx & 127;
    WtW[n * MSG + k] = f2bf_rne(Ww1[idx]);
    WtA[n * MSG + k] = f2bf_rne(Wa1[idx]);
  }
  if (idx < N) {
    x4[idx] = make_float4(x[3 * idx], x[3 * idx + 1], x[3 * idx + 2], 0.f);
  }
}

// ---- Kernel 2: fused edge MLPs + scatter.
// Block = 256 thr = 4 waves, TILE_M=64 edges. Wave w computes rows [16w,16w+16)
// x 128 hidden for both MLPs, fuses second linear in epilogue, then threads
// 0..63 scatter the weighted unit position diffs with 4 atomics/edge.
__global__ __launch_bounds__(256, 4)
void edge_mlp_kernel(const float* __restrict__ m_ij,
                     const unsigned short* __restrict__ WtW,
                     const unsigned short* __restrict__ WtA,
                     const float* __restrict__ bw1, const float* __restrict__ Ww2,
                     const float* __restrict__ bw2,
                     const float* __restrict__ ba1, const float* __restrict__ Wa2,
                     const float* __restrict__ ba2,
                     const int* __restrict__ src, const int* __restrict__ dst,
                     const float4* __restrict__ x4,
                     float4* __restrict__ num4, int E) {
  __shared__ __align__(16) unsigned short mlds[TILE_M * LDSTRIDE];
  __shared__ float wbuf[TILE_M];
  __shared__ float abuf[TILE_M];
  const int tid = threadIdx.x;
  const int e0 = blockIdx.x * TILE_M;

  // Issue the per-edge index loads + node gathers EARLY: their ~400cyc latency
  // overlaps the staging loads and is fully drained by the barrier.
  int sIdx = 0, dIdx = 0;
  float4 xs = make_float4(0, 0, 0, 0), xd = xs;
  if (tid < TILE_M) {
    int e = e0 + tid;
    if (e >= E) e = E - 1;
    sIdx = src[e];
    dIdx = dst[e];
    xs = x4[sIdx];
    xd = x4[dIdx];
  }

  // Stage 64x128 fp32 tile -> bf16 LDS. 2048 float4 chunks / 256 threads.
  #pragma unroll
  for (int i = 0; i < 8; ++i) {
    int c = i * 256 + tid;
    int row = c >> 5;
    int col4 = c & 31;
    int e = e0 + row;
    if (e >= E) e = E - 1;
    const float4 v = *(const float4*)(m_ij + ((size_t)e * MSG + col4 * 4));
    uint2 p;
    p.x = pack2bf_trunc(v.x, v.y);
    p.y = pack2bf_trunc(v.z, v.w);
    *(uint2*)(&mlds[row * LDSTRIDE + col4 * 4]) = p;
  }
  __syncthreads();

  const int w = tid >> 6;
  const int lane = tid & 63;
  const int quad = lane >> 4;
  const int l16 = lane & 15;
  const int r0 = w * 16;

  // A fragments (one 16-row strip per wave), preloaded once, reused by both MLPs.
  const unsigned short* ap = &mlds[(r0 + l16) * LDSTRIDE + quad * 8];
  bf16x8 A[4];
  #pragma unroll
  for (int kt = 0; kt < 4; ++kt) A[kt] = *(const bf16x8*)(ap + kt * 32);

  auto run_mlp = [&](const unsigned short* __restrict__ Wt,
                     const float* __restrict__ b1, const float* __restrict__ W2,
                     float b2) -> f32x4 {
    f32x4 acc[8];
    #pragma unroll
    for (int nt = 0; nt < 8; ++nt) acc[nt] = {0.f, 0.f, 0.f, 0.f};
    const unsigned short* bb = Wt + (size_t)l16 * MSG + quad * 8;
    #pragma unroll
    for (int nt = 0; nt < 8; ++nt) {
      #pragma unroll
      for (int kt = 0; kt < 4; ++kt) {
        bf16x8 B = *(const bf16x8*)(bb + (size_t)nt * 16 * MSG + kt * 32);
        acc[nt] = __builtin_amdgcn_mfma_f32_16x16x32_bf16(A[kt], B, acc[nt], 0, 0, 0);
      }
    }
    // Fused second linear: silu(h) dot W2 (lane holds cols n = nt*16+l16).
    f32x4 part = {0.f, 0.f, 0.f, 0.f};
    #pragma unroll
    for (int nt = 0; nt < 8; ++nt) {
      float b1v = b1[nt * 16 + l16];
      float w2v = W2[nt * 16 + l16];
      #pragma unroll
      for (int r = 0; r < 4; ++r) {
        float h = acc[nt][r] + b1v;
        float e = __expf(-h);
        part[r] += h * __builtin_amdgcn_rcpf(1.f + e) * w2v;  // silu(h)*w2
      }
    }
    // Reduce across the 16 lanes of each quad; rows = quad*4 + r.
    #pragma unroll
    for (int r = 0; r < 4; ++r) {
      #pragma unroll
      for (int off = 1; off < 16; off <<= 1)
        part[r] += __shfl_xor(part[r], off, 64);
      part[r] += b2;
    }
    return part;
  };

  f32x4 pw = run_mlp(WtW, bw1, Ww2, bw2[0]);
  f32x4 pa = run_mlp(WtA, ba1, Wa2, ba2[0]);

  #pragma unroll
  for (int r = 0; r < 4; ++r) {
    if (l16 == r) {  // one lane per quad writes its row's scalars
      wbuf[r0 + quad * 4 + r] = pw[r];
      abuf[r0 + quad * 4 + r] = pa[r];  // pre-exp attention logit
    }
  }
  __syncthreads();

  // Fused scatter: 64 edges by threads 0..63. Gathers (xs,xd) already in regs.
  if (tid < TILE_M) {
    int e = e0 + tid;
    if (e < E) {
      float wv = wbuf[tid];
      float av = __expf(abuf[tid]);
      float dx = xd.x - xs.x, dy = xd.y - xs.y, dz = xd.z - xs.z;
      float nrm = fmaxf(sqrtf(dx * dx + dy * dy + dz * dz), 1e-12f);
      float s = wv * av / nrm;
      float* np = (float*)(num4 + sIdx);
      atomicAdd(np + 0, dx * s);
      atomicAdd(np + 1, dy * s);
      atomicAdd(np + 2, dz * s);
      atomicAdd(np + 3, av);  // a_i accumulates in .w
    }
  }
}

// ---- Kernel 3: per-node finalize. out = x + num/a_i  (a_i==0 -> no edges -> x).
__global__ void finalize_kernel(const float* __restrict__ x,
                                const float4* __restrict__ num4,
                                float* __restrict__ out, int N) {
  int n = blockIdx.x * blockDim.x + threadIdx.x;
  if (n >= N) return;
  float4 v = num4[n];
  float inv = (v.w != 0.f) ? 1.f / v.w : 0.f;
  out[3 * n + 0] = x[3 * n + 0] + v.x * inv;
  out[3 * n + 1] = x[3 * n + 1] + v.y * inv;
  out[3 * n + 2] = x[3 * n + 2] + v.z * inv;
}

extern "C" void kernel_launch(void* const* d_in, const int* in_sizes, int n_in,
                              void* d_out, int out_size, void* d_ws, size_t ws_size,
                              hipStream_t stream) {
  const float* x    = (const float*)d_in[0];
  const float* m_ij = (const float*)d_in[1];
  const int*   edges = (const int*)d_in[2];
  const float* Ww1 = (const float*)d_in[3];
  const float* bw1 = (const float*)d_in[4];
  const float* Ww2 = (const float*)d_in[5];
  const float* bw2 = (const float*)d_in[6];
  const float* Wa1 = (const float*)d_in[7];
  const float* ba1 = (const float*)d_in[8];
  const float* Wa2 = (const float*)d_in[9];
  const float* ba2 = (const float*)d_in[10];

  const int N = in_sizes[0] / 3;
  const int E = in_sizes[1] / MSG;
  const int* src = edges;      // edges[0] = receiver
  const int* dst = edges + E;  // edges[1] = neighbor

  char* p = (char*)d_ws;
  unsigned short* WtW = (unsigned short*)p; p += (size_t)MSG * MSG * 2;
  unsigned short* WtA = (unsigned short*)p; p += (size_t)MSG * MSG * 2;
  float4* x4   = (float4*)p; p += (size_t)N * 16;
  float4* num4 = (float4*)p; p += (size_t)N * 16;

  float* out = (float*)d_out;

  hipMemsetAsync(num4, 0, (size_t)N * 16, stream);
  int prepN = (N > MSG * MSG) ? N : MSG * MSG;
  prep_kernel<<<(prepN + 255) / 256, 256, 0, stream>>>(Ww1, Wa1, x, WtW, WtA, x4, N);
  edge_mlp_kernel<<<(E + TILE_M - 1) / TILE_M, 256, 0, stream>>>(
      m_ij, WtW, WtA, bw1, Ww2, bw2, ba1, Wa2, ba2, src, dst, x4, num4, E);
  finalize_kernel<<<(N + 255) / 256, 256, 0, stream>>>(x, num4, out, N);
}